// Round 3
// baseline (12818.053 us; speedup 1.0000x reference)
//
#include <hip/hip_runtime.h>
#include <stdint.h>

// ---------- helpers ----------
__device__ __forceinline__ float bflo(uint32_t u){ union{uint32_t i; float f;}v; v.i = u<<16; return v.f; }
__device__ __forceinline__ float bfhi(uint32_t u){ union{uint32_t i; float f;}v; v.i = u & 0xffff0000u; return v.f; }
__device__ __forceinline__ uint16_t f2bf(float f){
  union{float f; uint32_t i;}v; v.f = f;
  uint32_t x = v.i;
  x += 0x7fffu + ((x>>16)&1u);
  return (uint16_t)(x>>16);
}

// ---------- prep: zero y, copy hidden -> h0, repack w_ih to stride-516 ----------
__global__ void prep_kernel(const float* __restrict__ hidden, const float* __restrict__ w_ih,
                            float* __restrict__ y, float* __restrict__ h0, float* __restrict__ w_ihp){
  int idx = blockIdx.x*blockDim.x + threadIdx.x;
  int n = gridDim.x*blockDim.x;
  for (int i=idx; i<4096; i+=n) y[i] = 0.f;
  for (int i=idx; i<32768; i+=n) h0[i] = hidden[i];
  for (int i=idx; i<1536*516; i+=n){
    int j = i/516, c = i - j*516;
    w_ihp[i] = (c<513) ? w_ih[(size_t)j*513 + c] : 0.f;
  }
}

// ---------- enc echo (runs AFTER the loop; K/V live in this region during the loop) ----------
__global__ void copy_enc_kernel(const float4* __restrict__ src, float4* __restrict__ dst, int n4){
  int idx = blockIdx.x*blockDim.x + threadIdx.x;
  int stride = gridDim.x*blockDim.x;
  for (int i=idx; i<n4; i+=stride) dst[i] = src[i];
}

// ---------- K/V projection: out[b,head,s,d] = enc[b,s,:] . W[head*256+d,:]  (bf16 store) ----------
// 128x128 tile per block, transposed LDS (k-major) for float4 fragment reads.
__global__ __launch_bounds__(256) void kv_build_kernel(
    const float* __restrict__ enc, const float* __restrict__ Wk, const float* __restrict__ Wv,
    uint16_t* __restrict__ Kn, uint16_t* __restrict__ Vn)
{
  __shared__ float As[32][132];
  __shared__ float Ws[32][132];
  const int s0 = blockIdx.x*128;         // 8 tiles
  const int d0 = blockIdx.y*128;         // 4 tiles
  const int z  = blockIdx.z;             // 128 = 64 b * 2 tensors
  const int b  = z>>1;
  const float* __restrict__ W = (z&1) ? Wv : Wk;
  uint16_t* __restrict__ On   = (z&1) ? Vn : Kn;
  const int tid = threadIdx.x;
  const int ty = tid>>4, tx = tid&15;
  const int c = tid&31, rb = tid>>5;
  float acc[8][8];
  #pragma unroll
  for (int i=0;i<8;++i)
    #pragma unroll
    for (int j=0;j<8;++j) acc[i][j]=0.f;
  const float* encb = enc + (size_t)b*1024*512;
  for (int k0=0;k0<512;k0+=32){
    #pragma unroll
    for (int p=0;p<16;++p){
      int r = p*8 + rb;
      As[c][r] = encb[(size_t)(s0+r)*512 + k0 + c];
      Ws[c][r] = W[(size_t)(d0+r)*512 + k0 + c];
    }
    __syncthreads();
    #pragma unroll
    for (int kk=0;kk<32;++kk){
      float4 a0 = *(const float4*)&As[kk][ty*4];
      float4 a1 = *(const float4*)&As[kk][64+ty*4];
      float4 w0 = *(const float4*)&Ws[kk][tx*4];
      float4 w1 = *(const float4*)&Ws[kk][64+tx*4];
      float av[8] = {a0.x,a0.y,a0.z,a0.w,a1.x,a1.y,a1.z,a1.w};
      float wv[8] = {w0.x,w0.y,w0.z,w0.w,w1.x,w1.y,w1.z,w1.w};
      #pragma unroll
      for (int i=0;i<8;++i)
        #pragma unroll
        for (int j=0;j<8;++j)
          acc[i][j] = fmaf(av[i], wv[j], acc[i][j]);
    }
    __syncthreads();
  }
  #pragma unroll
  for (int i=0;i<8;++i){
    int s = s0 + ty*4 + (i&3) + (i>>2)*64;
    #pragma unroll
    for (int j=0;j<8;++j){
      int d = d0 + tx*4 + (j&3) + (j>>2)*64;
      int head = d>>8, dh = d&255;
      On[(((size_t)b*2+head)*1024 + s)*256 + dh] = f2bf(acc[i][j]);
    }
  }
}

// ---------- attention (per step): grid (chunk=2, head=2, b=64) x 512 ----------
// computes q = h.Wq^T (scaled), chunk scores, partial softmax (m,l), partial ctx
__global__ __launch_bounds__(512) void attn_kernel(
    const uint16_t* __restrict__ Kn, const uint16_t* __restrict__ Vn,
    const float* __restrict__ h_in, const float* __restrict__ Wq,
    float* __restrict__ ctxp, float* __restrict__ ml)
{
  const int ch = blockIdx.x, head = blockIdx.y, b = blockIdx.z;
  const int tid = threadIdx.x;
  __shared__ float h_s[512];
  __shared__ float q_s[256];
  __shared__ float p_s[512];
  __shared__ float cpa[2048];   // [8][256]
  __shared__ float red[17];
  h_s[tid] = h_in[b*512 + tid];
  __syncthreads();
  { // q: pairs of threads per output d
    int d = tid>>1, hf = tid&1;
    const float4* wr = (const float4*)(Wq + (size_t)(head*256+d)*512 + hf*256);
    const float* hb = h_s + hf*256;
    float s = 0.f;
    #pragma unroll 8
    for (int i=0;i<64;++i){
      float4 w = wr[i];
      s = fmaf(w.x, hb[4*i+0], s); s = fmaf(w.y, hb[4*i+1], s);
      s = fmaf(w.z, hb[4*i+2], s); s = fmaf(w.w, hb[4*i+3], s);
    }
    s += __shfl_xor(s, 1);
    if (hf==0) q_s[d] = s * 0.0625f;   // 1/sqrt(256)
  }
  __syncthreads();
  const uint16_t* Kb = Kn + ((size_t)(b*2+head)*1024 + ch*512)*256;
  { // scores: 4 lanes per row, 4 passes of 128 rows
    int qd = tid&3, rbase = tid>>2;
    for (int p=0;p<4;++p){
      int r = p*128 + rbase;
      const uint4* Kr = (const uint4*)(Kb + (size_t)r*256);
      float s=0.f;
      #pragma unroll
      for (int u=0;u<8;++u){
        uint4 v = Kr[qd + 4*u];
        const float* qq = q_s + (qd+4*u)*8;
        s = fmaf(bflo(v.x), qq[0], s); s = fmaf(bfhi(v.x), qq[1], s);
        s = fmaf(bflo(v.y), qq[2], s); s = fmaf(bfhi(v.y), qq[3], s);
        s = fmaf(bflo(v.z), qq[4], s); s = fmaf(bfhi(v.z), qq[5], s);
        s = fmaf(bflo(v.w), qq[6], s); s = fmaf(bfhi(v.w), qq[7], s);
      }
      s += __shfl_xor(s,1); s += __shfl_xor(s,2);
      if (qd==0) p_s[r] = s;
    }
  }
  __syncthreads();
  float sc = p_s[tid];
  float m;
  { // block max (512 thr)
    float v = sc;
    #pragma unroll
    for (int o=32;o;o>>=1) v = fmaxf(v, __shfl_xor(v,o));
    if ((tid&63)==0) red[tid>>6] = v;
    __syncthreads();
    if (tid==0){ float mm=red[0]; for(int i=1;i<8;++i) mm=fmaxf(mm,red[i]); red[16]=mm; }
    __syncthreads();
    m = red[16];
  }
  float pv = __expf(sc - m);
  float l;
  { // block sum
    float v = pv;
    #pragma unroll
    for (int o=32;o;o>>=1) v += __shfl_xor(v,o);
    if ((tid&63)==0) red[8+(tid>>6)] = v;
    __syncthreads();
    if (tid==0){ float ss=0.f; for(int i=0;i<8;++i) ss+=red[8+i]; red[16]=ss; }
    __syncthreads();
    l = red[16];
  }
  p_s[tid] = pv;     // own slot, no sync needed before
  __syncthreads();
  const uint16_t* Vb = Vn + ((size_t)(b*2+head)*1024 + ch*512)*256;
  { // partial ctx: 8 s-groups x 64 d-quads
    int d4 = (tid&63)*4, sh = tid>>6;
    float a0=0,a1=0,a2=0,a3=0;
    for (int s2=sh*64; s2<sh*64+64; ++s2){
      float pw = p_s[s2];
      uint2 v = *(const uint2*)(Vb + (size_t)s2*256 + d4);
      a0 = fmaf(pw, bflo(v.x), a0); a1 = fmaf(pw, bfhi(v.x), a1);
      a2 = fmaf(pw, bflo(v.y), a2); a3 = fmaf(pw, bfhi(v.y), a3);
    }
    cpa[sh*256 + d4+0]=a0; cpa[sh*256 + d4+1]=a1;
    cpa[sh*256 + d4+2]=a2; cpa[sh*256 + d4+3]=a3;
  }
  __syncthreads();
  if (tid<256){
    float s=0.f;
    #pragma unroll
    for (int sh=0;sh<8;++sh) s += cpa[sh*256 + tid];
    ctxp[((size_t)(b*2+head)*2 + ch)*256 + tid] = s;  // unnormalized
  }
  if (tid==0){
    size_t mb = ((size_t)(b*2+head)*2 + ch)*2;
    ml[mb] = m; ml[mb+1] = l;
  }
}

// ---------- combine softmax chunks + ctx@Wo^T -> xin (per b) ----------
__global__ __launch_bounds__(256) void ctxo_kernel(
    const float* __restrict__ ctxp, const float* __restrict__ ml,
    const float* __restrict__ X, const float* __restrict__ Wo,
    float* __restrict__ xin, int t)
{
  const int b = blockIdx.x; const int tid = threadIdx.x;
  __shared__ float ctx_s[512];
  #pragma unroll
  for (int head=0; head<2; ++head){
    size_t base = (size_t)(b*2+head)*2;
    float m0 = ml[base*2+0], l0 = ml[base*2+1];
    float m1 = ml[base*2+2], l1 = ml[base*2+3];
    float mm = fmaxf(m0,m1);
    float w0 = __expf(m0-mm), w1 = __expf(m1-mm);
    float linv = 1.f/(w0*l0 + w1*l1);
    float c0 = ctxp[base*256 + tid];
    float c1 = ctxp[(base+1)*256 + tid];
    ctx_s[head*256+tid] = (w0*c0 + w1*c1)*linv;
  }
  __syncthreads();
  for (int j=tid; j<512; j+=256){
    const float4* wr = (const float4*)(Wo + (size_t)j*512);
    float s=0.f;
    #pragma unroll 8
    for (int i=0;i<128;++i){
      float4 w = wr[i];
      s = fmaf(w.x, ctx_s[4*i+0], s); s = fmaf(w.y, ctx_s[4*i+1], s);
      s = fmaf(w.z, ctx_s[4*i+2], s); s = fmaf(w.w, ctx_s[4*i+3], s);
    }
    xin[(size_t)b*516 + j] = s;
  }
  if (tid==0){
    xin[(size_t)b*516+512] = X[b*64 + t];
    xin[(size_t)b*516+513] = 0.f; xin[(size_t)b*516+514] = 0.f; xin[(size_t)b*516+515] = 0.f;
  }
}

// ---------- GRU cell: grid (jslice=8, btile=16) x 256 ; 4 b x 64 j per block ----------
__global__ __launch_bounds__(256) void gru_kernel(
    const float* __restrict__ xin_g, const float* __restrict__ h_in, float* __restrict__ h_out,
    const float* __restrict__ w_ihp, const float* __restrict__ w_hh,
    const float* __restrict__ b_ih, const float* __restrict__ b_hh,
    const float* __restrict__ Wd, const float* __restrict__ bd,
    float* __restrict__ y, int t)
{
  const int j0 = blockIdx.x*64, b0 = blockIdx.y*4;
  const int tid = threadIdx.x;
  __shared__ float xin_s[4][516];
  __shared__ float h_s[4][512];
  for (int bb2=0; bb2<4; ++bb2){
    for (int c2=tid; c2<516; c2+=256) xin_s[bb2][c2] = xin_g[(size_t)(b0+bb2)*516 + c2];
    for (int c2=tid; c2<512; c2+=256) h_s[bb2][c2]   = h_in[(size_t)(b0+bb2)*512 + c2];
  }
  __syncthreads();
  const int bb = tid>>6, jj = tid&63;   // whole wave shares bb
  const int j = j0 + jj, b = b0 + bb;
  const float* xs = xin_s[bb];
  const float* hs = h_s[bb];
  float gi[3], gh[3];
  #pragma unroll
  for (int g=0; g<3; ++g){
    const float4* wr = (const float4*)(w_ihp + (size_t)(g*512 + j)*516);
    float s = 0.f;
    #pragma unroll 4
    for (int i=0;i<129;++i){
      float4 w = wr[i];
      s = fmaf(w.x, xs[4*i+0], s); s = fmaf(w.y, xs[4*i+1], s);
      s = fmaf(w.z, xs[4*i+2], s); s = fmaf(w.w, xs[4*i+3], s);
    }
    gi[g] = s + b_ih[g*512 + j];
    const float4* wh = (const float4*)(w_hh + (size_t)(g*512 + j)*512);
    float sh = 0.f;
    #pragma unroll 4
    for (int i=0;i<128;++i){
      float4 w = wh[i];
      sh = fmaf(w.x, hs[4*i+0], sh); sh = fmaf(w.y, hs[4*i+1], sh);
      sh = fmaf(w.z, hs[4*i+2], sh); sh = fmaf(w.w, hs[4*i+3], sh);
    }
    gh[g] = sh + b_hh[g*512 + j];
  }
  float r = 1.f/(1.f + __expf(-(gi[0]+gh[0])));
  float z = 1.f/(1.f + __expf(-(gi[1]+gh[1])));
  float n = tanhf(gi[2] + r*gh[2]);
  float hn = (1.f - z)*n + z*hs[j];
  h_out[(size_t)b*512 + j] = hn;
  float part = hn * Wd[j];
  #pragma unroll
  for (int o=32;o>=1;o>>=1) part += __shfl_xor(part, o);
  if (jj==0){
    float add = part + ((blockIdx.x==0) ? bd[0] : 0.f);
    atomicAdd(y + b*64 + t, add);
  }
}

// ---------- final h copy ----------
__global__ void fin_kernel(const float* __restrict__ hfin, float* __restrict__ dst){
  int i = blockIdx.x*blockDim.x + threadIdx.x;
  if (i < 32768) dst[i] = hfin[i];
}

extern "C" void kernel_launch(void* const* d_in, const int* in_sizes, int n_in,
                              void* d_out, int out_size, void* d_ws, size_t ws_size,
                              hipStream_t stream)
{
  const float* X    = (const float*)d_in[0];
  const float* enc  = (const float*)d_in[1];
  const float* hid  = (const float*)d_in[2];
  const float* Wq   = (const float*)d_in[3];
  const float* Wk   = (const float*)d_in[4];
  const float* Wv   = (const float*)d_in[5];
  const float* Wo   = (const float*)d_in[6];
  const float* w_ih = (const float*)d_in[7];
  const float* w_hh = (const float*)d_in[8];
  const float* b_ih = (const float*)d_in[9];
  const float* b_hh = (const float*)d_in[10];
  const float* Wd   = (const float*)d_in[11];
  const float* bd   = (const float*)d_in[12];
  float* out = (float*)d_out;

  // K/V (bf16) live in the enc-echo region of d_out during the loop (134217728 B exactly);
  // enc echo is written AFTER the loop.
  uint16_t* Kn = (uint16_t*)(out + 4096);
  uint16_t* Vn = Kn + 33554432;

  char* ws = (char*)d_ws;
  float* h0   = (float*)(ws + 0);        // 131072 B
  float* h1   = (float*)(ws + 131072);   // 131072 B
  float* cp   = (float*)(ws + 262144);   // 262144 B  [64][2][2][256]
  float* ml   = (float*)(ws + 524288);   // 4096 B    [64][2][2][2]
  float* wihp = (float*)(ws + 528384);   // 3170304 B [1536][516]
  float* xin  = (float*)(ws + 3698688);  // 132096 B  [64][516]

  prep_kernel<<<dim3(512), dim3(256), 0, stream>>>(hid, w_ih, out, h0, wihp);
  kv_build_kernel<<<dim3(8,4,128), dim3(256), 0, stream>>>(enc, Wk, Wv, Kn, Vn);

  float* hb[2] = {h0, h1};
  for (int t=0; t<64; ++t){
    const float* hi = hb[t&1];
    float* ho = hb[1-(t&1)];
    attn_kernel<<<dim3(2,2,64), dim3(512), 0, stream>>>(Kn, Vn, hi, Wq, cp, ml);
    ctxo_kernel<<<dim3(64), dim3(256), 0, stream>>>(cp, ml, X, Wo, xin, t);
    gru_kernel<<<dim3(8,16), dim3(256), 0, stream>>>(xin, hi, ho, wihp, w_hh, b_ih, b_hh, Wd, bd, out, t);
  }
  // overwrite K/V region with the enc echo
  copy_enc_kernel<<<dim3(4096), dim3(256), 0, stream>>>((const float4*)enc, (float4*)(out + 4096), 8388608);
  fin_kernel<<<dim3(128), dim3(256), 0, stream>>>(h0, out + 4096 + 33554432);
}

// Round 4
// 8519.041 us; speedup vs baseline: 1.5046x; 1.5046x over previous
//
#include <hip/hip_runtime.h>
#include <hip/hip_fp8.h>
#include <stdint.h>

typedef __attribute__((ext_vector_type(8))) short short8v;
typedef __attribute__((ext_vector_type(4))) float f32x4;

// ---------- helpers ----------
__device__ __forceinline__ float bflo(uint32_t u){ union{uint32_t i; float f;}v; v.i = u<<16; return v.f; }
__device__ __forceinline__ float bfhi(uint32_t u){ union{uint32_t i; float f;}v; v.i = u & 0xffff0000u; return v.f; }
__device__ __forceinline__ uint16_t f2bf(float f){
  union{float f; uint32_t i;}v; v.f = f;
  uint32_t x = v.i;
  x += 0x7fffu + ((x>>16)&1u);
  return (uint16_t)(x>>16);
}
__device__ __forceinline__ uint8_t f2fp8(float f){
  return __builtin_bit_cast(uint8_t, __hip_fp8_e4m3(f));
}
__device__ __forceinline__ float fp82f(uint8_t b){
  return (float)__builtin_bit_cast(__hip_fp8_e4m3, b);
}

// ---------- prep: zero y, copy hidden -> h0, convert weights to bf16 ----------
__global__ void prep_kernel(const float* __restrict__ hidden, const float* __restrict__ w_ih,
                            const float* __restrict__ w_hh, const float* __restrict__ Wo,
                            float* __restrict__ y, float* __restrict__ h0,
                            uint16_t* __restrict__ wihp, uint16_t* __restrict__ whhb,
                            uint16_t* __restrict__ wob){
  int idx = blockIdx.x*blockDim.x + threadIdx.x;
  int n = gridDim.x*blockDim.x;
  for (int i=idx; i<4096; i+=n) y[i] = 0.f;
  for (int i=idx; i<32768; i+=n) h0[i] = hidden[i];
  for (int i=idx; i<1536*520; i+=n){
    int j = i/520, c = i - j*520;
    wihp[i] = (c<513) ? f2bf(w_ih[(size_t)j*513 + c]) : (uint16_t)0;
  }
  for (int i=idx; i<1536*512; i+=n) whhb[i] = f2bf(w_hh[i]);
  for (int i=idx; i<512*512; i+=n)  wob[i]  = f2bf(Wo[i]);
}

// ---------- enc echo (runs AFTER the loop; K/V live in this region during the loop) ----------
__global__ void copy_enc_kernel(const float4* __restrict__ src, float4* __restrict__ dst, int n4){
  int idx = blockIdx.x*blockDim.x + threadIdx.x;
  int stride = gridDim.x*blockDim.x;
  for (int i=idx; i<n4; i+=stride) dst[i] = src[i];
}

// ---------- K/V projection via bf16 MFMA: out[b,head,s,d] = enc[b,s,:].W[head*256+d,:] (fp8 store)
// 128x128 tile per block, 4 waves, mfma_f32_16x16x32_bf16.
__global__ __launch_bounds__(256) void kv_build_kernel(
    const float* __restrict__ enc, const float* __restrict__ Wk, const float* __restrict__ Wv,
    uint8_t* __restrict__ Kf, uint8_t* __restrict__ Vf)
{
  __shared__ uint16_t As[128][40];   // 32 k + 8 pad
  __shared__ uint16_t Bs[128][40];
  const int s0 = blockIdx.x*128;     // 8
  const int d0 = blockIdx.y*128;     // 4
  const int z  = blockIdx.z;         // 128 = 64 b * 2 tensors
  const int b  = z>>1;
  const float* __restrict__ W = (z&1) ? Wv : Wk;
  uint8_t* __restrict__ On    = (z&1) ? Vf : Kf;
  const int tid = threadIdx.x;
  const int wv = tid>>6, lane = tid&63;
  const int r = tid>>1, hh = (tid&1)*16;    // staging: row 0..127, k-offset 0/16
  const float* encb = enc + (size_t)b*1024*512;

  f32x4 acc[2][8];
  #pragma unroll
  for (int i=0;i<2;++i)
    #pragma unroll
    for (int j=0;j<8;++j) acc[i][j] = (f32x4){0.f,0.f,0.f,0.f};

  const int fr = lane&15, kq = (lane>>4)*8;

  for (int k0=0;k0<512;k0+=32){
    const float4* sa = (const float4*)(encb + (size_t)(s0+r)*512 + k0 + hh);
    const float4* sb = (const float4*)(W    + (size_t)(d0+r)*512 + k0 + hh);
    float4 va[4], vb[4];
    #pragma unroll
    for (int q=0;q<4;++q){ va[q]=sa[q]; vb[q]=sb[q]; }
    __syncthreads();   // previous iter's fragment reads done before overwrite
    uint16_t* pa = &As[r][hh];
    uint16_t* pb = &Bs[r][hh];
    #pragma unroll
    for (int q=0;q<4;++q){
      pa[4*q+0]=f2bf(va[q].x); pa[4*q+1]=f2bf(va[q].y); pa[4*q+2]=f2bf(va[q].z); pa[4*q+3]=f2bf(va[q].w);
      pb[4*q+0]=f2bf(vb[q].x); pb[4*q+1]=f2bf(vb[q].y); pb[4*q+2]=f2bf(vb[q].z); pb[4*q+3]=f2bf(vb[q].w);
    }
    __syncthreads();
    short8v af[2], bfr[8];
    af[0] = *(const short8v*)&As[wv*32 +      fr][kq];
    af[1] = *(const short8v*)&As[wv*32 + 16 + fr][kq];
    #pragma unroll
    for (int n2=0;n2<8;++n2) bfr[n2] = *(const short8v*)&Bs[n2*16 + fr][kq];
    #pragma unroll
    for (int mi=0;mi<2;++mi)
      #pragma unroll
      for (int n2=0;n2<8;++n2)
        acc[mi][n2] = __builtin_amdgcn_mfma_f32_16x16x32_bf16(af[mi], bfr[n2], acc[mi][n2], 0,0,0);
  }
  // epilogue: D row = (lane>>4)*4+reg, col = lane&15
  const int rq = (lane>>4)*4;
  #pragma unroll
  for (int mi=0;mi<2;++mi){
    #pragma unroll
    for (int reg=0; reg<4; ++reg){
      int s = s0 + wv*32 + mi*16 + rq + reg;
      #pragma unroll
      for (int n2=0;n2<8;++n2){
        int d = d0 + n2*16 + fr;
        int head = d>>8, dh = d&255;
        On[(((size_t)b*2+head)*1024 + s)*256 + dh] = f2fp8(acc[mi][n2][reg]);
      }
    }
  }
}

// ---------- attention (per step): grid (chunk=2, head=2, b=64) x 512, fp8 K/V ----------
__global__ __launch_bounds__(512) void attn_kernel(
    const uint8_t* __restrict__ Kf, const uint8_t* __restrict__ Vf,
    const float* __restrict__ h_in, const float* __restrict__ Wq,
    float* __restrict__ ctxp, float* __restrict__ ml)
{
  const int ch = blockIdx.x, head = blockIdx.y, b = blockIdx.z;
  const int tid = threadIdx.x;
  __shared__ float h_s[512];
  __shared__ float q_s[256];
  __shared__ float p_s[512];
  __shared__ float cpa[2048];   // [8][256]
  __shared__ float red[17];
  h_s[tid] = h_in[b*512 + tid];
  __syncthreads();
  { // q: pairs of threads per output d
    int d = tid>>1, hf = tid&1;
    const float4* wr = (const float4*)(Wq + (size_t)(head*256+d)*512 + hf*256);
    const float* hb = h_s + hf*256;
    float s = 0.f;
    #pragma unroll 8
    for (int i=0;i<64;++i){
      float4 w = wr[i];
      s = fmaf(w.x, hb[4*i+0], s); s = fmaf(w.y, hb[4*i+1], s);
      s = fmaf(w.z, hb[4*i+2], s); s = fmaf(w.w, hb[4*i+3], s);
    }
    s += __shfl_xor(s, 1);
    if (hf==0) q_s[d] = s * 0.0625f;   // 1/sqrt(256)
  }
  __syncthreads();
  const uint8_t* Kb = Kf + ((size_t)(b*2+head)*1024 + ch*512)*256;
  { // scores: 4 lanes per row, 4 passes of 128 rows; row = 256 fp8 = 16 uint4
    int qd = tid&3, rbase = tid>>2;
    for (int p=0;p<4;++p){
      int r = p*128 + rbase;
      const uint4* Kr = (const uint4*)(Kb + (size_t)r*256);
      float s=0.f;
      #pragma unroll
      for (int u=0;u<4;++u){
        uint4 v = Kr[qd + 4*u];
        const float* qq = q_s + (qd+4*u)*16;
        uint32_t w;
        w = v.x;
        s = fmaf(fp82f(w&255), qq[0], s);  s = fmaf(fp82f((w>>8)&255), qq[1], s);
        s = fmaf(fp82f((w>>16)&255), qq[2], s); s = fmaf(fp82f(w>>24), qq[3], s);
        w = v.y;
        s = fmaf(fp82f(w&255), qq[4], s);  s = fmaf(fp82f((w>>8)&255), qq[5], s);
        s = fmaf(fp82f((w>>16)&255), qq[6], s); s = fmaf(fp82f(w>>24), qq[7], s);
        w = v.z;
        s = fmaf(fp82f(w&255), qq[8], s);  s = fmaf(fp82f((w>>8)&255), qq[9], s);
        s = fmaf(fp82f((w>>16)&255), qq[10], s); s = fmaf(fp82f(w>>24), qq[11], s);
        w = v.w;
        s = fmaf(fp82f(w&255), qq[12], s); s = fmaf(fp82f((w>>8)&255), qq[13], s);
        s = fmaf(fp82f((w>>16)&255), qq[14], s); s = fmaf(fp82f(w>>24), qq[15], s);
      }
      s += __shfl_xor(s,1); s += __shfl_xor(s,2);
      if (qd==0) p_s[r] = s;
    }
  }
  __syncthreads();
  float sc = p_s[tid];
  float m;
  { // block max (512 thr)
    float v = sc;
    #pragma unroll
    for (int o=32;o;o>>=1) v = fmaxf(v, __shfl_xor(v,o));
    if ((tid&63)==0) red[tid>>6] = v;
    __syncthreads();
    if (tid==0){ float mm=red[0]; for(int i=1;i<8;++i) mm=fmaxf(mm,red[i]); red[16]=mm; }
    __syncthreads();
    m = red[16];
  }
  float pv = __expf(sc - m);
  float l;
  { // block sum
    float v = pv;
    #pragma unroll
    for (int o=32;o;o>>=1) v += __shfl_xor(v,o);
    if ((tid&63)==0) red[8+(tid>>6)] = v;
    __syncthreads();
    if (tid==0){ float ss=0.f; for(int i=0;i<8;++i) ss+=red[8+i]; red[16]=ss; }
    __syncthreads();
    l = red[16];
  }
  p_s[tid] = pv;
  __syncthreads();
  const uint8_t* Vb = Vf + ((size_t)(b*2+head)*1024 + ch*512)*256;
  { // partial ctx: 8 s-groups x 64 d-quads; 4 fp8 per uint32
    int d4 = (tid&63)*4, sh = tid>>6;
    float a0=0,a1=0,a2=0,a3=0;
    for (int s2=sh*64; s2<sh*64+64; ++s2){
      float pw = p_s[s2];
      uint32_t v = *(const uint32_t*)(Vb + (size_t)s2*256 + d4);
      a0 = fmaf(pw, fp82f(v&255), a0);       a1 = fmaf(pw, fp82f((v>>8)&255), a1);
      a2 = fmaf(pw, fp82f((v>>16)&255), a2); a3 = fmaf(pw, fp82f(v>>24), a3);
    }
    cpa[sh*256 + d4+0]=a0; cpa[sh*256 + d4+1]=a1;
    cpa[sh*256 + d4+2]=a2; cpa[sh*256 + d4+3]=a3;
  }
  __syncthreads();
  if (tid<256){
    float s=0.f;
    #pragma unroll
    for (int sh=0;sh<8;++sh) s += cpa[sh*256 + tid];
    ctxp[((size_t)(b*2+head)*2 + ch)*256 + tid] = s;  // unnormalized
  }
  if (tid==0){
    size_t mb = ((size_t)(b*2+head)*2 + ch)*2;
    ml[mb] = m; ml[mb+1] = l;
  }
}

// ---------- combine softmax chunks + ctx@Wo^T (bf16 Wo) -> xin (per b) ----------
__global__ __launch_bounds__(256) void ctxo_kernel(
    const float* __restrict__ ctxp, const float* __restrict__ ml,
    const float* __restrict__ X, const uint16_t* __restrict__ wob,
    float* __restrict__ xin, int t)
{
  const int b = blockIdx.x; const int tid = threadIdx.x;
  __shared__ float ctx_s[512];
  #pragma unroll
  for (int head=0; head<2; ++head){
    size_t base = (size_t)(b*2+head)*2;
    float m0 = ml[base*2+0], l0 = ml[base*2+1];
    float m1 = ml[base*2+2], l1 = ml[base*2+3];
    float mm = fmaxf(m0,m1);
    float w0 = __expf(m0-mm), w1 = __expf(m1-mm);
    float linv = 1.f/(w0*l0 + w1*l1);
    float c0 = ctxp[base*256 + tid];
    float c1 = ctxp[(base+1)*256 + tid];
    ctx_s[head*256+tid] = (w0*c0 + w1*c1)*linv;
  }
  __syncthreads();
  for (int j=tid; j<512; j+=256){
    const uint4* wr = (const uint4*)(wob + (size_t)j*512);
    float s=0.f;
    #pragma unroll 4
    for (int i=0;i<64;++i){
      uint4 w = wr[i];
      s = fmaf(bflo(w.x), ctx_s[8*i+0], s); s = fmaf(bfhi(w.x), ctx_s[8*i+1], s);
      s = fmaf(bflo(w.y), ctx_s[8*i+2], s); s = fmaf(bfhi(w.y), ctx_s[8*i+3], s);
      s = fmaf(bflo(w.z), ctx_s[8*i+4], s); s = fmaf(bfhi(w.z), ctx_s[8*i+5], s);
      s = fmaf(bflo(w.w), ctx_s[8*i+6], s); s = fmaf(bfhi(w.w), ctx_s[8*i+7], s);
    }
    xin[(size_t)b*516 + j] = s;
  }
  if (tid==0){
    xin[(size_t)b*516+512] = X[b*64 + t];
    xin[(size_t)b*516+513] = 0.f; xin[(size_t)b*516+514] = 0.f; xin[(size_t)b*516+515] = 0.f;
  }
}

// ---------- GRU cell (bf16 weights): grid (jslice=8, btile=16) x 256 ----------
__global__ __launch_bounds__(256) void gru_kernel(
    const float* __restrict__ xin_g, const float* __restrict__ h_in, float* __restrict__ h_out,
    const uint16_t* __restrict__ wihp, const uint16_t* __restrict__ whhb,
    const float* __restrict__ b_ih, const float* __restrict__ b_hh,
    const float* __restrict__ Wd, const float* __restrict__ bd,
    float* __restrict__ y, int t)
{
  const int j0 = blockIdx.x*64, b0 = blockIdx.y*4;
  const int tid = threadIdx.x;
  __shared__ float xin_s[4][520];
  __shared__ float h_s[4][512];
  for (int bb2=0; bb2<4; ++bb2){
    for (int c2=tid; c2<520; c2+=256) xin_s[bb2][c2] = (c2<516) ? xin_g[(size_t)(b0+bb2)*516 + c2] : 0.f;
    for (int c2=tid; c2<512; c2+=256) h_s[bb2][c2]   = h_in[(size_t)(b0+bb2)*512 + c2];
  }
  __syncthreads();
  const int bb = tid>>6, jj = tid&63;   // whole wave shares bb
  const int j = j0 + jj, b = b0 + bb;
  const float* xs = xin_s[bb];
  const float* hs = h_s[bb];
  float gi[3], gh[3];
  #pragma unroll
  for (int g=0; g<3; ++g){
    const uint4* wr = (const uint4*)(wihp + (size_t)(g*512 + j)*520);
    float s = 0.f;
    #pragma unroll 5
    for (int i=0;i<65;++i){
      uint4 w = wr[i];
      s = fmaf(bflo(w.x), xs[8*i+0], s); s = fmaf(bfhi(w.x), xs[8*i+1], s);
      s = fmaf(bflo(w.y), xs[8*i+2], s); s = fmaf(bfhi(w.y), xs[8*i+3], s);
      s = fmaf(bflo(w.z), xs[8*i+4], s); s = fmaf(bfhi(w.z), xs[8*i+5], s);
      s = fmaf(bflo(w.w), xs[8*i+6], s); s = fmaf(bfhi(w.w), xs[8*i+7], s);
    }
    gi[g] = s + b_ih[g*512 + j];
    const uint4* wh = (const uint4*)(whhb + (size_t)(g*512 + j)*512);
    float sh = 0.f;
    #pragma unroll 4
    for (int i=0;i<64;++i){
      uint4 w = wh[i];
      sh = fmaf(bflo(w.x), hs[8*i+0], sh); sh = fmaf(bfhi(w.x), hs[8*i+1], sh);
      sh = fmaf(bflo(w.y), hs[8*i+2], sh); sh = fmaf(bfhi(w.y), hs[8*i+3], sh);
      sh = fmaf(bflo(w.z), hs[8*i+4], sh); sh = fmaf(bfhi(w.z), hs[8*i+5], sh);
      sh = fmaf(bflo(w.w), hs[8*i+6], sh); sh = fmaf(bfhi(w.w), hs[8*i+7], sh);
    }
    gh[g] = sh + b_hh[g*512 + j];
  }
  float r = 1.f/(1.f + __expf(-(gi[0]+gh[0])));
  float z = 1.f/(1.f + __expf(-(gi[1]+gh[1])));
  float n = tanhf(gi[2] + r*gh[2]);
  float hn = (1.f - z)*n + z*hs[j];
  h_out[(size_t)b*512 + j] = hn;
  float part = hn * Wd[j];
  #pragma unroll
  for (int o=32;o>=1;o>>=1) part += __shfl_xor(part, o);
  if (jj==0){
    float add = part + ((blockIdx.x==0) ? bd[0] : 0.f);
    atomicAdd(y + b*64 + t, add);
  }
}

// ---------- final h copy ----------
__global__ void fin_kernel(const float* __restrict__ hfin, float* __restrict__ dst){
  int i = blockIdx.x*blockDim.x + threadIdx.x;
  if (i < 32768) dst[i] = hfin[i];
}

extern "C" void kernel_launch(void* const* d_in, const int* in_sizes, int n_in,
                              void* d_out, int out_size, void* d_ws, size_t ws_size,
                              hipStream_t stream)
{
  const float* X    = (const float*)d_in[0];
  const float* enc  = (const float*)d_in[1];
  const float* hid  = (const float*)d_in[2];
  const float* Wq   = (const float*)d_in[3];
  const float* Wk   = (const float*)d_in[4];
  const float* Wv   = (const float*)d_in[5];
  const float* Wo   = (const float*)d_in[6];
  const float* w_ih = (const float*)d_in[7];
  const float* w_hh = (const float*)d_in[8];
  const float* b_ih = (const float*)d_in[9];
  const float* b_hh = (const float*)d_in[10];
  const float* Wd   = (const float*)d_in[11];
  const float* bd   = (const float*)d_in[12];
  float* out = (float*)d_out;

  // K/V (fp8 e4m3) live in the enc-echo region of d_out during the loop (67 MB of 134 MB);
  // enc echo is written AFTER the loop.
  uint8_t* Kf = (uint8_t*)(out + 4096);
  uint8_t* Vf = Kf + 33554432;

  char* ws = (char*)d_ws;
  float*    h0   = (float*)(ws + 0);           // 131072 B
  float*    h1   = (float*)(ws + 131072);      // 131072 B
  float*    cp   = (float*)(ws + 262144);      // 262144 B  [64][2][2][256]
  float*    ml   = (float*)(ws + 524288);      // 4096 B
  uint16_t* wihp = (uint16_t*)(ws + 528384);   // 1597440 B [1536][520] bf16
  uint16_t* whhb = (uint16_t*)(ws + 2125824);  // 1572864 B [1536][512] bf16
  uint16_t* wob  = (uint16_t*)(ws + 3698688);  // 524288 B  [512][512]  bf16
  float*    xin  = (float*)(ws + 4222976);     // 132096 B  [64][516]

  prep_kernel<<<dim3(512), dim3(256), 0, stream>>>(hid, w_ih, w_hh, Wo, out, h0, wihp, whhb, wob);
  kv_build_kernel<<<dim3(8,4,128), dim3(256), 0, stream>>>(enc, Wk, Wv, Kf, Vf);

  float* hb[2] = {h0, h1};
  for (int t=0; t<64; ++t){
    const float* hi = hb[t&1];
    float* ho = hb[1-(t&1)];
    attn_kernel<<<dim3(2,2,64), dim3(512), 0, stream>>>(Kf, Vf, hi, Wq, cp, ml);
    ctxo_kernel<<<dim3(64), dim3(256), 0, stream>>>(cp, ml, X, wob, xin, t);
    gru_kernel<<<dim3(8,16), dim3(256), 0, stream>>>(xin, hi, ho, wihp, whhb, b_ih, b_hh, Wd, bd, out, t);
  }
  // overwrite K/V region with the enc echo
  copy_enc_kernel<<<dim3(4096), dim3(256), 0, stream>>>((const float4*)enc, (float4*)(out + 4096), 8388608);
  fin_kernel<<<dim3(128), dim3(256), 0, stream>>>(h0, out + 4096 + 33554432);
}